// Round 8
// baseline (71.805 us; speedup 1.0000x reference)
//
#include <hip/hip_runtime.h>

typedef __attribute__((ext_vector_type(8))) short bf16x8;
typedef __attribute__((ext_vector_type(4))) float f32x4;

#define EMB_DIM 400
#define OUT_CH  6
#define ARITY   3
#define BATCH   8192
#define W_OUT   200
#define FC_LEN  1200
#define NT      25      // 16-wide col tiles (400/16)
#define NKS     7       // k-steps of 32 (K=200 padded to 224)
#define BM      32      // batch rows per block
#define NBLK    256     // grid size == CU count (co-residency required)
#define NSLICE  (ARITY * NT * NKS)   // 525 pack slices
#define NTASK   (ARITY * BM * 100)   // 9600 float4 gather tasks per block
#define NLD     19                   // ceil(NTASK / 512)

static __device__ __forceinline__ ushort f2bf(float f) {
    union { float f; uint u; } v; v.f = f;
    uint u = v.u;
    return (ushort)((u + 0x7FFF + ((u >> 16) & 1)) >> 16);   // RNE
}

// Mb layout: for (i*NT+t, kk): 64 lanes x 8 bf16; lane l, elem j holds
//   B[w = kk*32 + (l>>4)*8 + j][d = t*16 + (l&15)]  (w>=200 -> 0)
__global__ __launch_bounds__(512)
void hype_fused(const int* __restrict__ r_idx, const int* __restrict__ E_mat,
                const float* __restrict__ ms, const float* __restrict__ bs,
                const float* __restrict__ E_emb, const float* __restrict__ R_emb,
                const float* __restrict__ fc2_W, const float* __restrict__ fc2_b,
                const float* __restrict__ fc_W, const float* __restrict__ fc_b,
                ushort* __restrict__ Mb, uint* __restrict__ done,
                float* __restrict__ out) {
    __shared__ ushort es[ARITY * 2 * NKS * 64 * 8];   // 43008 B
    __shared__ float Bt[32][16];
    __shared__ float sm_ms[BM * 3], sm_bs[BM * 3], sm_fcb[EMB_DIM];
    __shared__ int   sm_rb[BM], sm_ent[BM * 3];
    __shared__ float osum[4][BM];

    const int tid = threadIdx.x;
    const int b0 = blockIdx.x * BM;

    // small per-block loads (sync provided by the pack loop's barriers)
    if (tid < BM * 3) {
        sm_ms[tid]  = ms[b0 * 3 + tid];
        sm_bs[tid]  = bs[b0 * 3 + tid];
        sm_ent[tid] = E_mat[b0 * 3 + tid];
    }
    if (tid >= 96 && tid < 96 + BM) sm_rb[tid - 96] = r_idx[b0 + tid - 96] * EMB_DIM;
    for (int z = tid; z < EMB_DIM; z += 512) sm_fcb[z] = fc_b[z];

    uint* esu = reinterpret_cast<uint*>(es);
    // zero the K-pad: kk=6, lane>=16 regions: 6 pairs * 192 uints
    for (int z = tid; z < ARITY * 2 * 192; z += 512) {
        int pair = z / 192, off = z % 192;
        esu[(pair * NKS + 6) * 256 + 64 + off] = 0;
    }

    // ---- Phase P: pack this block's share of Mb (2-3 slices) ----
    for (int s = blockIdx.x; s < NSLICE; s += NBLK) {
        const int bt = s / NKS, kk = s % NKS;   // bt = i*25 + t
        const int i = bt / NT, t = bt % NT;
        if (tid < 256) {
            float kc[OUT_CH];
#pragma unroll
            for (int c = 0; c < OUT_CH; ++c) kc[c] = fc2_W[c * 4 + i] + fc2_b[c];
            const int dd = tid >> 4, wl = tid & 15;
            const int d = t * 16 + dd;
#pragma unroll
            for (int ss = 0; ss < 2; ++ss) {
                int w = kk * 32 + wl + 16 * ss;
                float v = 0.f;
                if (w < W_OUT) {
#pragma unroll
                    for (int c = 0; c < OUT_CH; ++c)
                        v = fmaf(kc[c], fc_W[d * FC_LEN + c * W_OUT + w], v);
                }
                Bt[wl + 16 * ss][dd] = v;
            }
        }
        __syncthreads();
        if (tid < 64) {
            const int l = tid;
            ushort vals[8];
#pragma unroll
            for (int j = 0; j < 8; ++j)
                vals[j] = f2bf(Bt[(l >> 4) * 8 + j][l & 15]);
            *reinterpret_cast<uint4*>(Mb + ((size_t)(bt * NKS + kk) * 64 + l) * 8) =
                *reinterpret_cast<const uint4*>(vals);
        }
        __syncthreads();
    }
    __threadfence();                       // device-scope release of Mb writes
    if (tid == 0) atomicAdd(done, 1u);

    // ---- Phase G: batched gather (issue all 19 random loads first) ----
    float4 vreg[NLD];
#pragma unroll
    for (int k = 0; k < NLD; ++k) {
        int tq = tid + k * 512;
        if (tq < NTASK) {
            int q = tq % 100;
            int p = tq / 100;
            int i = p / BM, r = p % BM;
            int ent = sm_ent[r * 3 + i];
            vreg[k] = *reinterpret_cast<const float4*>(
                E_emb + (size_t)ent * EMB_DIM + 4 * q);
        }
    }
#pragma unroll
    for (int k = 0; k < NLD; ++k) {
        int tq = tid + k * 512;
        if (tq < NTASK) {
            int q = tq % 100;
            int p = tq / 100;
            int i = p / BM, r = p % BM;
            int w = 2 * q;                    // covers w, w+1 (same 8-block)
            int kk = w >> 5;
            int lsub = (w >> 3) & 3;
            int j = w & 7;                    // even
            int rg = r >> 4, rl = r & 15;
            int l = lsub * 16 + rl;
            uint pk = (uint)f2bf(vreg[k].x) | ((uint)f2bf(vreg[k].z) << 16);
            esu[(((i * 2 + rg) * NKS + kk) * 64 + l) * 4 + (j >> 1)] = pk;
        }
    }
    __syncthreads();

    const int wid = tid >> 6;
    const int lane = tid & 63;
    const int rg = wid & 1, cg = wid >> 1;     // rg: row-group, cg: col-group
    const int cl = lane & 15;                   // col within tile
    const int rql = lane >> 4;                  // row quad

    // preload all A fragments for this wave's 16 rows (3 i * 7 kk = 84 VGPR)
    bf16x8 afrag[ARITY][NKS];
#pragma unroll
    for (int i = 0; i < ARITY; ++i)
#pragma unroll
        for (int kk = 0; kk < NKS; ++kk)
            afrag[i][kk] = *reinterpret_cast<const bf16x8*>(
                es + (((i * 2 + rg) * NKS + kk) * 64 + lane) * 8);

    // register-cache epilogue scalars (R2-style)
    float msv[ARITY][4], bsv[ARITY][4];
    int rbv[4];
#pragma unroll
    for (int r_ = 0; r_ < 4; ++r_) {
        int row = rg * 16 + rql * 4 + r_;
#pragma unroll
        for (int i = 0; i < ARITY; ++i) {
            msv[i][r_] = sm_ms[row * 3 + i];
            bsv[i][r_] = sm_bs[row * 3 + i];
        }
        rbv[r_] = sm_rb[row];
    }

    // ---- wait until all blocks published their Mb slices (hidden by gather) ----
    if (tid == 0) {
        while (__hip_atomic_load(done, __ATOMIC_ACQUIRE, __HIP_MEMORY_SCOPE_AGENT)
               < (uint)NBLK) {
            __builtin_amdgcn_s_sleep(8);
        }
    }
    __syncthreads();

    float rowsum[4] = {0.f, 0.f, 0.f, 0.f};
    for (int t = cg; t < NT; t += 4) {
        const int d = t * 16 + cl;
        // early-issue epilogue operands (independent of MFMA chain)
        float Rr[4];
#pragma unroll
        for (int r_ = 0; r_ < 4; ++r_) Rr[r_] = R_emb[rbv[r_] + d];
        const float fcb = sm_fcb[d];

        f32x4 acc[ARITY];
#pragma unroll
        for (int i = 0; i < ARITY; ++i) {
            f32x4 a = {0.f, 0.f, 0.f, 0.f};
            const ushort* bp = Mb + ((size_t)(i * NT + t) * NKS * 64 + lane) * 8;
#pragma unroll
            for (int kk = 0; kk < NKS; ++kk) {
                bf16x8 bfr = *reinterpret_cast<const bf16x8*>(bp + kk * 512);
                a = __builtin_amdgcn_mfma_f32_16x16x32_bf16(afrag[i][kk], bfr, a, 0, 0, 0);
            }
            acc[i] = a;
        }
#pragma unroll
        for (int r_ = 0; r_ < 4; ++r_) {
            float e0 = fmaf(acc[0][r_] + fcb, msv[0][r_], bsv[0][r_]);
            float e1 = fmaf(acc[1][r_] + fcb, msv[1][r_], bsv[1][r_]);
            float e2 = fmaf(acc[2][r_] + fcb, msv[2][r_], bsv[2][r_]);
            rowsum[r_] = fmaf(e0 * e1 * e2, Rr[r_], rowsum[r_]);
        }
    }

#pragma unroll
    for (int m = 1; m < 16; m <<= 1)
#pragma unroll
        for (int r_ = 0; r_ < 4; ++r_)
            rowsum[r_] += __shfl_xor(rowsum[r_], m, 64);
    if (cl == 0) {
#pragma unroll
        for (int r_ = 0; r_ < 4; ++r_)
            osum[cg][rg * 16 + rql * 4 + r_] = rowsum[r_];
    }
    __syncthreads();
    if (tid < BM)
        out[b0 + tid] = osum[0][tid] + osum[1][tid] + osum[2][tid] + osum[3][tid];
}

extern "C" void kernel_launch(void* const* d_in, const int* in_sizes, int n_in,
                              void* d_out, int out_size, void* d_ws, size_t ws_size,
                              hipStream_t stream) {
    const int*   r_idx = (const int*)d_in[0];
    const int*   E_mat = (const int*)d_in[1];
    const float* ms    = (const float*)d_in[2];
    const float* bs    = (const float*)d_in[3];
    const float* E_emb = (const float*)d_in[4];
    const float* R_emb = (const float*)d_in[5];
    const float* fc2_W = (const float*)d_in[6];
    const float* fc2_b = (const float*)d_in[7];
    const float* fc_W  = (const float*)d_in[8];
    const float* fc_b  = (const float*)d_in[9];
    float*  out  = (float*)d_out;
    ushort* Mb   = (ushort*)d_ws;                      // 537600 B
    uint*   done = (uint*)((char*)d_ws + 537600);      // 4 B flag

    hipMemsetAsync(done, 0, sizeof(uint), stream);
    hype_fused<<<NBLK, 512, 0, stream>>>(r_idx, E_mat, ms, bs, E_emb, R_emb,
                                         fc2_W, fc2_b, fc_W, fc_b, Mb, done, out);
}

// Round 9
// 38.589 us; speedup vs baseline: 1.8608x; 1.8608x over previous
//
#include <hip/hip_runtime.h>

typedef __attribute__((ext_vector_type(8))) short bf16x8;
typedef __attribute__((ext_vector_type(4))) float f32x4;

#define EMB_DIM 400
#define OUT_CH  6
#define ARITY   3
#define BATCH   8192
#define W_OUT   200
#define FC_LEN  1200
#define NT      25      // 16-wide col tiles (400/16)
#define NKS     7       // k-steps of 32 (K=200 padded to 224)
#define BM      32      // batch rows per block
#define NSLICE  (ARITY * NT * NKS)     // 525 pack slices
#define PACK_BLKS 263                  // ceil(525/2) pack blocks (2 slices each)
#define GATHER_BLKS (BATCH / BM)       // 256 gather blocks
#define NTASK   (ARITY * BM * 100)     // 9600 float4 gather tasks per block
#define NLD     19                     // ceil(NTASK / 512)
#define AF_U16_PER_BLK (ARITY * 2 * NKS * 64 * 8)   // 21504 ushorts = 43008 B

static __device__ __forceinline__ ushort f2bf(float f) {
    union { float f; uint u; } v; v.f = f;
    uint u = v.u;
    return (ushort)((u + 0x7FFF + ((u >> 16) & 1)) >> 16);   // RNE
}

// Mb layout: for (i*NT+t, kk): 64 lanes x 8 bf16; lane l, elem j holds
//   B[w = kk*32 + (l>>4)*8 + j][d = t*16 + (l&15)]  (w>=200 -> 0)
// Af layout: per gather-block g (rows g*32..g*32+31): fragment (i, rg, kk):
//   u16 offset = g*21504 + (((i*2+rg)*NKS + kk)*64 + l)*8 + j
__global__ __launch_bounds__(512)
void prep2(const int* __restrict__ E_mat, const float* __restrict__ E_emb,
           const float* __restrict__ fc2_W, const float* __restrict__ fc2_b,
           const float* __restrict__ fc_W,
           ushort* __restrict__ Mb, ushort* __restrict__ Af) {
    __shared__ float Bt[2][32][16];
    __shared__ int   sm_ent[BM * 3];
    const int tid = threadIdx.x;

    if (blockIdx.x < PACK_BLKS) {
        // ---- pack: 2 slices per block (R6-proven math) ----
        const int half = tid >> 8, htid = tid & 255;
        const int s = blockIdx.x * 2 + half;
        const bool valid = s < NSLICE;
        int i = 0, t = 0, kk = 0, bt = 0;
        if (valid) { bt = s / NKS; kk = s % NKS; i = bt / NT; t = bt % NT; }
        if (valid) {
            float kc[OUT_CH];
#pragma unroll
            for (int c = 0; c < OUT_CH; ++c) kc[c] = fc2_W[c * 4 + i] + fc2_b[c];
            const int dd = htid >> 4, wl = htid & 15;
            const int d = t * 16 + dd;
#pragma unroll
            for (int ss = 0; ss < 2; ++ss) {
                int w = kk * 32 + wl + 16 * ss;
                float v = 0.f;
                if (w < W_OUT) {
#pragma unroll
                    for (int c = 0; c < OUT_CH; ++c)
                        v = fmaf(kc[c], fc_W[d * FC_LEN + c * W_OUT + w], v);
                }
                Bt[half][wl + 16 * ss][dd] = v;
            }
        }
        __syncthreads();
        if (valid && htid < 64) {
            const int l = htid;
            ushort vals[8];
#pragma unroll
            for (int j = 0; j < 8; ++j)
                vals[j] = f2bf(Bt[half][(l >> 4) * 8 + j][l & 15]);
            *reinterpret_cast<uint4*>(Mb + ((size_t)(bt * NKS + kk) * 64 + l) * 8) =
                *reinterpret_cast<const uint4*>(vals);
        }
    } else {
        // ---- gather: R6-proven batched gather, target = global Af ----
        const int g = blockIdx.x - PACK_BLKS;
        const int b0 = g * BM;
        if (tid < BM * 3) sm_ent[tid] = E_mat[b0 * 3 + tid];
        uint* Afu = reinterpret_cast<uint*>(Af) + (size_t)g * (AF_U16_PER_BLK / 2);
        // zero the K-pad: kk=6, lanes>=16: 6 (i,rg) pairs * 192 uints
        for (int z = tid; z < ARITY * 2 * 192; z += 512) {
            int pair = z / 192, off = z % 192;
            Afu[(pair * NKS + 6) * 256 + 64 + off] = 0;
        }
        __syncthreads();   // sm_ent ready

        float4 vreg[NLD];
#pragma unroll
        for (int k = 0; k < NLD; ++k) {
            int tq = tid + k * 512;
            if (tq < NTASK) {
                int q = tq % 100;
                int p = tq / 100;
                int i = p / BM, r = p % BM;
                int ent = sm_ent[r * 3 + i];
                vreg[k] = *reinterpret_cast<const float4*>(
                    E_emb + (size_t)ent * EMB_DIM + 4 * q);
            }
        }
#pragma unroll
        for (int k = 0; k < NLD; ++k) {
            int tq = tid + k * 512;
            if (tq < NTASK) {
                int q = tq % 100;
                int p = tq / 100;
                int i = p / BM, r = p % BM;
                int w = 2 * q;                    // covers w, w+1 (same 8-block)
                int kk = w >> 5;
                int lsub = (w >> 3) & 3;
                int j = w & 7;                    // even
                int rg = r >> 4, rl = r & 15;
                int l = lsub * 16 + rl;
                uint pk = (uint)f2bf(vreg[k].x) | ((uint)f2bf(vreg[k].z) << 16);
                Afu[(((i * 2 + rg) * NKS + kk) * 64 + l) * 4 + (j >> 1)] = pk;
            }
        }
    }
}

__global__ __launch_bounds__(512)
void gemm2(const int* __restrict__ r_idx, const float* __restrict__ ms,
           const float* __restrict__ bs, const float* __restrict__ R_emb,
           const float* __restrict__ fc_b, const ushort* __restrict__ Mb,
           const ushort* __restrict__ Af, float* __restrict__ out) {
    __shared__ float osum[4][BM];
    const int tid = threadIdx.x;
    const int b0 = blockIdx.x * BM;
    const int wid = tid >> 6;
    const int lane = tid & 63;
    const int rg = wid & 1, cg = wid >> 1;
    const int cl = lane & 15;
    const int rql = lane >> 4;

    // preload this wave's A fragments straight from Af (21 coalesced dwordx4)
    const ushort* Ab = Af + (size_t)blockIdx.x * AF_U16_PER_BLK;
    bf16x8 afrag[ARITY][NKS];
#pragma unroll
    for (int i = 0; i < ARITY; ++i)
#pragma unroll
        for (int kk = 0; kk < NKS; ++kk)
            afrag[i][kk] = *reinterpret_cast<const bf16x8*>(
                Ab + (((i * 2 + rg) * NKS + kk) * 64 + lane) * 8);

    // register-cache epilogue scalars
    float msv[ARITY][4], bsv[ARITY][4];
    int rbv[4];
#pragma unroll
    for (int r_ = 0; r_ < 4; ++r_) {
        int b = b0 + rg * 16 + rql * 4 + r_;
#pragma unroll
        for (int i = 0; i < ARITY; ++i) {
            msv[i][r_] = ms[b * 3 + i];
            bsv[i][r_] = bs[b * 3 + i];
        }
        rbv[r_] = r_idx[b] * EMB_DIM;
    }

    float rowsum[4] = {0.f, 0.f, 0.f, 0.f};
    for (int t = cg; t < NT; t += 4) {
        f32x4 acc[ARITY];
#pragma unroll
        for (int i = 0; i < ARITY; ++i) {
            f32x4 a = {0.f, 0.f, 0.f, 0.f};
            const ushort* bp = Mb + ((size_t)(i * NT + t) * NKS * 64 + lane) * 8;
#pragma unroll
            for (int kk = 0; kk < NKS; ++kk) {
                bf16x8 bfr = *reinterpret_cast<const bf16x8*>(bp + kk * 512);
                a = __builtin_amdgcn_mfma_f32_16x16x32_bf16(afrag[i][kk], bfr, a, 0, 0, 0);
            }
            acc[i] = a;
        }
        const int d = t * 16 + cl;
        const float fcb = fc_b[d];
#pragma unroll
        for (int r_ = 0; r_ < 4; ++r_) {
            float Rr = R_emb[rbv[r_] + d];
            float e0 = fmaf(acc[0][r_] + fcb, msv[0][r_], bsv[0][r_]);
            float e1 = fmaf(acc[1][r_] + fcb, msv[1][r_], bsv[1][r_]);
            float e2 = fmaf(acc[2][r_] + fcb, msv[2][r_], bsv[2][r_]);
            rowsum[r_] = fmaf(e0 * e1 * e2, Rr, rowsum[r_]);
        }
    }

#pragma unroll
    for (int m = 1; m < 16; m <<= 1)
#pragma unroll
        for (int r_ = 0; r_ < 4; ++r_)
            rowsum[r_] += __shfl_xor(rowsum[r_], m, 64);
    if (cl == 0) {
#pragma unroll
        for (int r_ = 0; r_ < 4; ++r_)
            osum[cg][rg * 16 + rql * 4 + r_] = rowsum[r_];
    }
    __syncthreads();
    if (tid < BM)
        out[b0 + tid] = osum[0][tid] + osum[1][tid] + osum[2][tid] + osum[3][tid];
}

extern "C" void kernel_launch(void* const* d_in, const int* in_sizes, int n_in,
                              void* d_out, int out_size, void* d_ws, size_t ws_size,
                              hipStream_t stream) {
    const int*   r_idx = (const int*)d_in[0];
    const int*   E_mat = (const int*)d_in[1];
    const float* ms    = (const float*)d_in[2];
    const float* bs    = (const float*)d_in[3];
    const float* E_emb = (const float*)d_in[4];
    const float* R_emb = (const float*)d_in[5];
    const float* fc2_W = (const float*)d_in[6];
    const float* fc2_b = (const float*)d_in[7];
    const float* fc_W  = (const float*)d_in[8];
    const float* fc_b  = (const float*)d_in[9];
    float*  out = (float*)d_out;
    ushort* Mb  = (ushort*)d_ws;                       // 537600 B
    ushort* Af  = (ushort*)((char*)d_ws + 537600);     // 256*43008 = 11010048 B

    prep2<<<PACK_BLKS + GATHER_BLKS, 512, 0, stream>>>(E_mat, E_emb, fc2_W, fc2_b,
                                                       fc_W, Mb, Af);
    gemm2<<<GATHER_BLKS, 512, 0, stream>>>(r_idx, ms, bs, R_emb, fc_b, Mb, Af, out);
}